// Round 8
// baseline (418.220 us; speedup 1.0000x reference)
//
#include <hip/hip_runtime.h>
#include <hip/hip_bf16.h>
#include <cstdint>
#include <cstddef>

typedef unsigned short u16;
typedef unsigned int u32;
typedef short short8 __attribute__((ext_vector_type(8)));
typedef short short4v __attribute__((ext_vector_type(4)));
typedef __bf16 bf16x8 __attribute__((ext_vector_type(8)));
typedef float v4f __attribute__((ext_vector_type(4)));
typedef float v16f __attribute__((ext_vector_type(16)));

#define NSAMP 65536
#define FEAT_PAD 1824   // 228 groups of 8

// ---- Layouts ----
// feats_t [rt=s>>4][g=kp>>3][r=s&15][e=kp&7]: elem addr = rt*29184 + g*128 + r*8 + e
// w1t_t   [ct=n>>4][g][c][e]:                 addr = ct*29184 + g*128 + c*8 + e
// h1      ROW-MAJOR [s][n] (65536 x 256)
// w2t_t   [ct][g][c][e] (128 cols, K=256):    addr = ct*4096  + g*128 + c*8 + e
// w3t_t   [ct][g][c][e] (64 cols, K=128):     addr = ct*2048  + g*128 + c*8 + e
// Intra-gram kp permutation (validated R3-R9):
//   kp in [512,1536): kp = 512 + lane*16 + rr  <-> orig 512 + i*32 + j,
//        j=lane&31, i=(rr&3)+8*(rr>>2)+4*(lane>>5)
//   kp in [1536,1792): kp = 1536 + lane*4 + rr <-> orig 1536 + i*16 + j,
//        j=lane&15, i=(lane>>4)*4+rr
//   sv at kp [1792,1808) natural, zeros [1808,1824)
// STORE DISCIPLINE (R2/R3): the 4 stores completing a lane's 64 B sector
// must issue back-to-back; any time-separation -> partial-line eviction ->
// WRITE amplification.
// STRUCTURE HISTORY: R5 fused feat (loads+grams+stores+svd per wave) = 147us
// local optimum. Split/overlap attempts (R2 dual-stream, R6/R7 grid-union)
// all regressed -- extra issue work costs more than phase overlap recovers.
// R8: gemm1 gains a 2-phase double-buffered K-loop (T3-minimal): STAGE(t+1)
// issued BEFORE compute(t), ONE barrier per tile. Previously STAGE->barrier->
// compute exposed full HBM latency every 32-K step (95us vs 43us mem floor).

__device__ __forceinline__ u16 f2bf(float f) {          // bit-twiddle RTNE (cold paths)
  union { float f; u32 u; } v; v.f = f;
  u32 r = (v.u + 0x7FFFu + ((v.u >> 16) & 1u)) >> 16;
  return (u16)r;
}
__device__ __forceinline__ u16 f2bf_h(float f) {        // HW RTNE cvt (hot paths)
  return __builtin_bit_cast(u16, (__bf16)f);
}
__device__ __forceinline__ float bf2f(u16 h) {
  union { u32 u; float f; } v; v.u = ((u32)h) << 16;
  return v.f;
}

__device__ __forceinline__ v4f mfma16(short8 a, short8 b, v4f c) {
  return __builtin_amdgcn_mfma_f32_16x16x32_bf16(
      __builtin_bit_cast(bf16x8, a), __builtin_bit_cast(bf16x8, b), c, 0, 0, 0);
}
__device__ __forceinline__ v16f mfma32(short8 a, short8 b, v16f c) {
  return __builtin_amdgcn_mfma_f32_32x32x16_bf16(
      __builtin_bit_cast(bf16x8, a), __builtin_bit_cast(bf16x8, b), c, 0, 0, 0);
}

// async global->LDS, 16 B/lane; per-lane global addr, wave-uniform LDS base
typedef __attribute__((address_space(1))) const void* gas_ptr;
typedef __attribute__((address_space(3))) void* las_ptr;
__device__ __forceinline__ void gl_lds16(const void* g, void* l) {
  __builtin_amdgcn_global_load_lds((gas_ptr)g, (las_ptr)l, 16, 0, 0);
}

// ---------------------------------------------------------------------------
// Weight prep -> fragment-tiled W1t/W2t/W3t. (unchanged)
// ---------------------------------------------------------------------------
__global__ void prep_kernel(const float* __restrict__ W1, const float* __restrict__ W2,
                            const float* __restrict__ W3,
                            u16* __restrict__ w1t, u16* __restrict__ w2t, u16* __restrict__ w3t) {
  int idx = blockIdx.x * 256 + threadIdx.x;
  if (idx < 256 * FEAT_PAD) {
    int n = idx / FEAT_PAD, kp = idx % FEAT_PAD;
    int k;
    if (kp < 512) {
      k = kp;
    } else if (kp < 1536) {
      int t = kp - 512, ln = t >> 4, rr = t & 15;
      int jj = ln & 31, q2 = ln >> 5;
      int i = (rr & 3) + 8 * (rr >> 2) + 4 * q2;
      k = 512 + i * 32 + jj;
    } else if (kp < 1792) {
      int t = kp - 1536, ln = t >> 2, rr = t & 3;
      int jj = ln & 15;
      int i = (ln >> 4) * 4 + rr;
      k = 1536 + i * 16 + jj;
    } else {
      k = kp;
    }
    size_t addr = (size_t)(n >> 4) * 29184 + (kp >> 3) * 128 + (n & 15) * 8 + (kp & 7);
    w1t[addr] = (kp < 1808) ? f2bf(W1[(size_t)k * 256 + n]) : (u16)0;
  }
  if (idx < 128 * 256) {
    int n = idx / 256, k = idx % 256;
    size_t addr = (size_t)(n >> 4) * 4096 + (k >> 3) * 128 + (n & 15) * 8 + (k & 7);
    w2t[addr] = f2bf(W2[k * 128 + n]);
  }
  if (idx < 64 * 128) {
    int n = idx / 128, k = idx % 128;
    size_t addr = (size_t)(n >> 4) * 2048 + (k >> 3) * 128 + (n & 15) * 8 + (k & 7);
    w3t[addr] = f2bf(W3[k * 64 + n]);
  }
}

// ---------------------------------------------------------------------------
// Fused SVD for 4 samples. R5 structure (LDS-pipe-lean):
// - Rotation transpose: 16 bpermutes; works on quad-rotation similarity
//   permutation of the gram (eigenvalues invariant; role jr=(j-4q)&15).
// - Broadcast-first Householder: 2 dependent shuffle stages/step; h, alpha,
//   beta, v computed locally in all lanes.
// - Division-free Sturm bisection (13 iters), dual-chain dots.
// ---------------------------------------------------------------------------
__device__ __forceinline__ void svd4(const v4f* aR, u16* tb, int s0, int lane) {
  const int j = lane & 15, bse = lane & 48, q = lane >> 4;
  const int jr = (j - 4 * q) & 15;          // role in the permuted frame
  int sig[16];                               // physical lane of role m
#pragma unroll
  for (int m = 0; m < 16; ++m) sig[m] = bse + ((m + 4 * q) & 15);

  // rotation transpose: a[c*4+r] = A'[c*4+r][jr] = A_q[((q+c)&3)*4+r][j]
  float a[16];
#pragma unroll
  for (int c = 0; c < 4; ++c) {
    const int srcq = (q - c) & 3;                 // sample reg this lane serves
    const int rd = ((q + c) & 3) * 16 + j;        // physical source lane
#pragma unroll
    for (int r = 0; r < 4; ++r) {
      float lo = (srcq & 1) ? aR[1][r] : aR[0][r];
      float hi = (srcq & 1) ? aR[3][r] : aR[2][r];
      float sel = (srcq & 2) ? hi : lo;
      a[c * 4 + r] = __shfl(sel, rd);
    }
  }

  float es[16];
#pragma unroll
  for (int i = 0; i < 16; ++i) es[i] = 0.f;

#pragma unroll
  for (int step = 0; step < 14; ++step) {
    const int i = 15 - step, l = i - 1;
    float xm = (jr <= l) ? a[i] : 0.f;
    // stage 1: broadcast row i (roles 0..l) to all lanes
    float xa[16];
#pragma unroll
    for (int m = 0; m < 16; ++m) xa[m] = (m < i) ? __shfl(xm, sig[m]) : 0.f;
    // h, alpha, beta computed redundantly (locally) in every lane
    float ha = 0.f, hb = 0.f;
#pragma unroll
    for (int m = 0; m < 16; m += 2) if (m < i) ha = fmaf(xa[m], xa[m], ha);
#pragma unroll
    for (int m = 1; m < 16; m += 2) if (m < i) hb = fmaf(xa[m], xa[m], hb);
    float h = ha + hb;
    float ul = xa[l];
    float sq = __builtin_amdgcn_sqrtf(h);
    float alpha = (ul >= 0.f) ? -sq : sq;
    float denom = h - ul * alpha;
    float beta = (h > 1e-30f) ? __builtin_amdgcn_rcpf(denom) : 0.f;
    float vq = (jr < l) ? xm : ((jr == l) ? (xm - alpha) : 0.f);
    xa[l] -= alpha;                      // xa[] now IS the v vector (m < i)
    es[i] = alpha;
    // p_j = beta * (A v)_j  (local dot, dual chain)
    float pa = 0.f, pb = 0.f;
#pragma unroll
    for (int m = 0; m < 16; m += 2) if (m < i) pa = fmaf(a[m], xa[m], pa);
#pragma unroll
    for (int m = 1; m < 16; m += 2) if (m < i) pb = fmaf(a[m], xa[m], pb);
    float p = (pa + pb) * beta;
    // stage 2: broadcast p (roles 0..l)
    float pp[16];
#pragma unroll
    for (int m = 0; m < 16; ++m) pp[m] = (m < i) ? __shfl(p, sig[m]) : 0.f;
    float Ka = 0.f, Kb = 0.f;
#pragma unroll
    for (int m = 0; m < 16; m += 2) if (m < i) Ka = fmaf(pp[m], xa[m], Ka);
#pragma unroll
    for (int m = 1; m < 16; m += 2) if (m < i) Kb = fmaf(pp[m], xa[m], Kb);
    float Ks = (Ka + Kb) * (0.5f * beta);
    float wsc = p - Ks * vq;             // this lane's w component
#pragma unroll
    for (int m = 0; m < 16; ++m) {
      if (m < i) {                       // row i skipped: entries dead after this step
        float wm = pp[m] - Ks * xa[m];
        a[m] -= xa[m] * wsc + wm * vq;
      }
    }
  }
  es[1] = __shfl(a[1], sig[0]);

  // diagonal broadcast (role m's diagonal from physical lane sig[m])
  float dd[16];
#pragma unroll
  for (int m = 0; m < 16; ++m) dd[m] = __shfl(a[m], sig[m]);
  float e2a[16];
  e2a[0] = 0.f;
#pragma unroll
  for (int k = 1; k < 16; ++k) e2a[k] = es[k] * es[k] + 1e-30f;
  float dmax = dd[0], emax = 0.f;
#pragma unroll
  for (int m = 1; m < 16; ++m) dmax = fmaxf(dmax, dd[m]);
#pragma unroll
  for (int k = 1; k < 16; ++k) emax = fmaxf(emax, fabsf(es[k]));

  // scale by 1/32 so det-recurrence magnitudes stay in fp32 range
  const float scl = 0.03125f;
#pragma unroll
  for (int m = 0; m < 16; ++m) dd[m] *= scl;
#pragma unroll
  for (int k = 1; k < 16; ++k) e2a[k] *= (scl * scl);

  float lo = 0.f, hi = (dmax + 2.f * emax + 1e-6f) * scl;
#pragma unroll 1
  for (int iter = 0; iter < 13; ++iter) {
    float mid = 0.5f * (lo + hi);
    // division-free Sturm: p_k = (d_k - mid) p_{k-1} - e2_k p_{k-2};
    // #eigs < mid = sign changes in (1, p_1, ..., p_16). Chain = 1 fma/step.
    float pm1 = 1.f, pc = dd[0] - mid;
    u32 cnt = __builtin_bit_cast(u32, pc) >> 31;
#pragma unroll
    for (int k = 1; k < 16; ++k) {
      float t = e2a[k] * pm1;
      float pn = fmaf(dd[k] - mid, pc, -t);
      cnt += ((__builtin_bit_cast(u32, pn) ^ __builtin_bit_cast(u32, pc)) >> 31);
      pm1 = pc; pc = pn;
    }
    if ((int)cnt > jr) hi = mid; else lo = mid;
  }
  float lam = 0.5f * (lo + hi) * 32.f;
  int t = 15 - jr;                      // descending order
  int s = s0 + q;                       // this quad's sample
  tb[(size_t)(224 + (t >> 3)) * 128 + (s & 15) * 8 + (t & 7)] =
      f2bf_h(__builtin_amdgcn_sqrtf(fmaxf(lam, 0.f)));
}

// ---------------------------------------------------------------------------
// Feature kernel: ONE 4-sample qtr per wave (16384 independent waves) WITH
// fused svd4 tail (R5-proven structure, 147 us). HW bf16 cvt in hot path.
// ---------------------------------------------------------------------------
__global__ __launch_bounds__(256) void feat_kernel(const float* __restrict__ x,
                                                   u16* __restrict__ feats) {
  const int lane = threadIdx.x & 63;
  const int wv = threadIdx.x >> 6;      // qtr index 0..3
  const int wid = blockIdx.x;           // tile 0..4095
  const int l15 = lane & 15, l31 = lane & 31, q4 = lane >> 4, q2 = lane >> 5;
  const int pbase = l15 * 32 + q4 * 8;
  u16* tb = feats + (size_t)wid * 29184;

  short8 sx[4], sc0[4], sc1[4];
  short4v sr4[4];
  v4f aR[4];
#pragma unroll
  for (int r8 = 0; r8 < 4; ++r8) {
    const int s = wid * 16 + wv * 4 + r8;
    const float* xs = x + (size_t)s * 512;
    float4 p0 = *(const float4*)(xs + pbase);
    float4 p1 = *(const float4*)(xs + pbase + 4);
    float t[8];
#pragma unroll
    for (int j = 0; j < 8; ++j) t[j] = xs[(q2 * 8 + j) * 32 + l31];

    short8 fp, ft;
    fp[0] = (short)f2bf_h(p0.x); fp[1] = (short)f2bf_h(p0.y);
    fp[2] = (short)f2bf_h(p0.z); fp[3] = (short)f2bf_h(p0.w);
    fp[4] = (short)f2bf_h(p1.x); fp[5] = (short)f2bf_h(p1.y);
    fp[6] = (short)f2bf_h(p1.z); fp[7] = (short)f2bf_h(p1.w);
#pragma unroll
    for (int j = 0; j < 8; ++j) ft[j] = (short)f2bf_h(t[j]);

    v4f accR; v16f accC;
#pragma unroll
    for (int r = 0; r < 4; ++r) accR[r] = 0.f;
#pragma unroll
    for (int r = 0; r < 16; ++r) accC[r] = 0.f;
    accR = mfma16(fp, fp, accR);   // Gr = P P^T (fp32)
    accC = mfma32(ft, ft, accC);   // Gc = P^T P

    sx[r8] = fp;
#pragma unroll
    for (int r = 0; r < 8; ++r) { sc0[r8][r] = (short)f2bf_h(accC[r]); sc1[r8][r] = (short)f2bf_h(accC[r + 8]); }
#pragma unroll
    for (int r = 0; r < 4; ++r) sr4[r8][r] = (short)f2bf_h(accR[r]);
    aR[r8] = accR;
  }

  // stores: all 4 hr per stream back-to-back; 4 waves co-write each 256 B
  // line concurrently (full-sector pattern, R1-proven)
  const int ho = wv * 4;
#pragma unroll
  for (int r8 = 0; r8 < 4; ++r8)
    *(short8*)(tb + (l15 * 4 + q4) * 128 + (ho + r8) * 8) = sx[r8];
#pragma unroll
  for (int r8 = 0; r8 < 4; ++r8)
    *(short8*)(tb + (64 + lane * 2) * 128 + (ho + r8) * 8) = sc0[r8];
#pragma unroll
  for (int r8 = 0; r8 < 4; ++r8)
    *(short8*)(tb + (65 + lane * 2) * 128 + (ho + r8) * 8) = sc1[r8];
#pragma unroll
  for (int r8 = 0; r8 < 4; ++r8)
    *(short4v*)(tb + (192 + (lane >> 1)) * 128 + (lane & 1) * 4 + (ho + r8) * 8) = sr4[r8];

  if (wv == 3 && lane < 32) {  // zero pad groups 226,227
    short8 z;
#pragma unroll
    for (int j = 0; j < 8; ++j) z[j] = 0;
    *(short8*)(tb + 226 * 128 + lane * 8) = z;
  }

  svd4(aR, tb, wid * 16 + ho, lane);  // sv for this wave's 4 samples
}

// ---------------------------------------------------------------------------
// GEMM1: h1 = relu(feats @ W1 + b1). M=65536, K=1824, N=256.
// R8: 2-phase double-buffered K-loop (T3-minimal). 48 KB LDS (2 bufs),
// (256,2) -> 2 blocks/CU (96 KB). Per tile: issue STAGE(t+1) FIRST, then
// ds_read+MFMA on buf[cur], then ONE __syncthreads() (its vmcnt drain lands
// after the compute phase -> HBM latency hidden under MFMA + co-resident
// block). Previously STAGE->barrier->compute exposed ~900cy per K-step.
// ---------------------------------------------------------------------------
__global__ __launch_bounds__(256, 2) void gemm1_kernel(const u16* __restrict__ feats,
                                                       const u16* __restrict__ w1t,
                                                       const float* __restrict__ b1,
                                                       u16* __restrict__ h1) {
  __shared__ __align__(16) u16 At[2 * 8 * 512];    // 16 KB  [buf][rt_local][g][r][e]
  __shared__ __align__(16) u16 Bt[2 * 16 * 512];   // 32 KB  [buf][ct_local][g][c][e]
  const int tid = threadIdx.x, lane = tid & 63, wv = tid >> 6;
  const int l15 = lane & 15, q4 = lane >> 4;
  const int m0 = blockIdx.x * 128;
  const int wm = (wv & 1) * 64, wn = (wv >> 1) * 128;

  const u16* gA[2];
#pragma unroll
  for (int j = 0; j < 2; ++j)
    gA[j] = feats + (size_t)((m0 >> 4) + wv * 2 + j) * 29184 + lane * 8;
  const u16* gB[4];
#pragma unroll
  for (int j = 0; j < 4; ++j)
    gB[j] = w1t + (size_t)(wv * 4 + j) * 29184 + lane * 8;

  v4f acc[4][8];
#pragma unroll
  for (int mt = 0; mt < 4; ++mt)
#pragma unroll
    for (int nt = 0; nt < 8; ++nt)
#pragma unroll
      for (int r = 0; r < 4; ++r) acc[mt][nt][r] = 0.f;

  const int NT = FEAT_PAD / 32;          // 57 K-tiles

  // prologue: stage tile 0 into buf 0
  {
#pragma unroll
    for (int j = 0; j < 2; ++j) gl_lds16(gA[j], At + (wv * 2 + j) * 512);
#pragma unroll
    for (int j = 0; j < 4; ++j) gl_lds16(gB[j], Bt + (wv * 4 + j) * 512);
  }
  __syncthreads();

  int cur = 0;
  for (int t = 0; t < NT; ++t) {
    // issue next tile's loads FIRST (latency hides under this tile's compute)
    if (t + 1 < NT) {
      const int go = (t + 1) * 512;
      const int nb = cur ^ 1;
#pragma unroll
      for (int j = 0; j < 2; ++j) gl_lds16(gA[j] + go, At + nb * 4096 + (wv * 2 + j) * 512);
#pragma unroll
      for (int j = 0; j < 4; ++j) gl_lds16(gB[j] + go, Bt + nb * 8192 + (wv * 4 + j) * 512);
    }

    const u16* Ab = At + cur * 4096;
    const u16* Bb = Bt + cur * 8192;
    short8 af[4], bfr[8];
#pragma unroll
    for (int mt = 0; mt < 4; ++mt)
      af[mt] = *(const short8*)(Ab + ((wv & 1) * 4 + mt) * 512 + q4 * 128 + l15 * 8);
#pragma unroll
    for (int nt = 0; nt < 8; ++nt)
      bfr[nt] = *(const short8*)(Bb + ((wv >> 1) * 8 + nt) * 512 + q4 * 128 + l15 * 8);
#pragma unroll
    for (int mt = 0; mt < 4; ++mt)
#pragma unroll
      for (int nt = 0; nt < 8; ++nt)
        acc[mt][nt] = mfma16(af[mt], bfr[nt], acc[mt][nt]);

    __syncthreads();   // one barrier/tile: drains prefetch (covered by compute)
    cur ^= 1;
  }

  // epilogue: bias+relu, row-major h1 (proven full-sector pattern)
#pragma unroll
  for (int mt = 0; mt < 4; ++mt)
#pragma unroll
    for (int nt = 0; nt < 8; ++nt) {
      int col = wn + nt * 16 + l15;
      float bias = b1[col];
#pragma unroll
      for (int r = 0; r < 4; ++r) {
        int row = m0 + wm + mt * 16 + q4 * 4 + r;
        h1[(size_t)row * 256 + col] = f2bf_h(fmaxf(acc[mt][nt][r] + bias, 0.f));
      }
    }
}

// ---------------------------------------------------------------------------
// GEMM23: fused layers 2-4, barrier-free; A-frags from ROW-MAJOR h1. (unchanged)
// ---------------------------------------------------------------------------
__global__ __launch_bounds__(256, 2) void gemm23_kernel(
    const u16* __restrict__ h1, const u16* __restrict__ w2t, const float* __restrict__ b2,
    const u16* __restrict__ w3t, const float* __restrict__ b3,
    const float* __restrict__ w4, const float* __restrict__ b4, float* __restrict__ out) {
  __shared__ __align__(16) u16 H2[128 * 136];
  const int tid = threadIdx.x, lane = tid & 63, wv = tid >> 6;
  const int l15 = lane & 15, q4 = lane >> 4;
  const int m0 = blockIdx.x * 128;

  const u16* pA[2];
#pragma unroll
  for (int mt = 0; mt < 2; ++mt)
    pA[mt] = h1 + (size_t)(m0 + wv * 32 + mt * 16 + l15) * 256 + q4 * 8;
  const u16* pB[8];
#pragma unroll
  for (int nt = 0; nt < 8; ++nt)
    pB[nt] = w2t + (size_t)nt * 4096 + q4 * 128 + l15 * 8;

  v4f acc[2][8];
#pragma unroll
  for (int mt = 0; mt < 2; ++mt)
#pragma unroll
    for (int nt = 0; nt < 8; ++nt)
#pragma unroll
      for (int r = 0; r < 4; ++r) acc[mt][nt][r] = 0.f;

#pragma unroll
  for (int kk = 0; kk < 8; ++kk) {
    short8 af[2], bfr[8];
#pragma unroll
    for (int mt = 0; mt < 2; ++mt) af[mt] = *(const short8*)(pA[mt] + kk * 32);
#pragma unroll
    for (int nt = 0; nt < 8; ++nt) bfr[nt] = *(const short8*)(pB[nt] + kk * 512);
#pragma unroll
    for (int mt = 0; mt < 2; ++mt)
#pragma unroll
      for (int nt = 0; nt < 8; ++nt)
        acc[mt][nt] = mfma16(af[mt], bfr[nt], acc[mt][nt]);
  }

#pragma unroll
  for (int mt = 0; mt < 2; ++mt)
#pragma unroll
    for (int nt = 0; nt < 8; ++nt) {
      int c = nt * 16 + l15;
      float bias = b2[c];
#pragma unroll
      for (int r = 0; r < 4; ++r) {
        int rl = wv * 32 + mt * 16 + q4 * 4 + r;
        H2[rl * 136 + c] = f2bf_h(fmaxf(acc[mt][nt][r] + bias, 0.f));
      }
    }

  v4f acc2[2][4];
#pragma unroll
  for (int mt = 0; mt < 2; ++mt)
#pragma unroll
    for (int nt = 0; nt < 4; ++nt)
#pragma unroll
      for (int r = 0; r < 4; ++r) acc2[mt][nt][r] = 0.f;
#pragma unroll
  for (int kk = 0; kk < 4; ++kk) {
    short8 af2[2], bf2v[4];
#pragma unroll
    for (int mt = 0; mt < 2; ++mt)
      af2[mt] = *(const short8*)(H2 + (wv * 32 + mt * 16 + l15) * 136 + kk * 32 + q4 * 8);
#pragma unroll
    for (int nt = 0; nt < 4; ++nt)
      bf2v[nt] = *(const short8*)(w3t + (size_t)nt * 2048 + (kk * 4 + q4) * 128 + l15 * 8);
#pragma unroll
    for (int mt = 0; mt < 2; ++mt)
#pragma unroll
      for (int nt = 0; nt < 4; ++nt)
        acc2[mt][nt] = mfma16(af2[mt], bf2v[nt], acc2[mt][nt]);
  }

  float b4v = b4[0];
#pragma unroll
  for (int mt = 0; mt < 2; ++mt)
#pragma unroll
    for (int r = 0; r < 4; ++r) {
      float p = 0.f;
#pragma unroll
      for (int nt = 0; nt < 4; ++nt) {
        int c = nt * 16 + l15;
        float h3 = fmaxf(acc2[mt][nt][r] + b3[c], 0.f);
        p += h3 * w4[c];
      }
      p += __shfl_xor(p, 1);
      p += __shfl_xor(p, 2);
      p += __shfl_xor(p, 4);
      p += __shfl_xor(p, 8);
      if (l15 == 0) {
        int row = m0 + wv * 32 + mt * 16 + q4 * 4 + r;
        out[row] = p + b4v;
      }
    }
}

// ---------------------------------------------------------------------------
extern "C" void kernel_launch(void* const* d_in, const int* in_sizes, int n_in,
                              void* d_out, int out_size, void* d_ws, size_t ws_size,
                              hipStream_t stream) {
  const float* x  = (const float*)d_in[0];
  const float* W1 = (const float*)d_in[1];
  const float* b1 = (const float*)d_in[2];
  const float* W2 = (const float*)d_in[3];
  const float* b2 = (const float*)d_in[4];
  const float* W3 = (const float*)d_in[5];
  const float* b3 = (const float*)d_in[6];
  const float* W4 = (const float*)d_in[7];
  const float* b4 = (const float*)d_in[8];
  float* out = (float*)d_out;

  char* ws = (char*)d_ws;
  u16* feats = (u16*)ws;                                  // 239,075,328 B
  u16* h1    = (u16*)(ws + 239075328ull);                 //  33,554,432 B (row-major)
  u16* w1t   = (u16*)(ws + 239075328ull + 33554432ull);   //     933,888 B
  u16* w2t   = (u16*)(ws + 239075328ull + 33554432ull + 933888ull);            // 65,536
  u16* w3t   = (u16*)(ws + 239075328ull + 33554432ull + 933888ull + 65536ull); // 16,384

  prep_kernel<<<1824, 256, 0, stream>>>(W1, W2, W3, w1t, w2t, w3t);
  feat_kernel<<<4096, 256, 0, stream>>>(x, feats);
  gemm1_kernel<<<512, 256, 0, stream>>>(feats, w1t, b1, h1);
  gemm23_kernel<<<512, 256, 0, stream>>>(h1, w2t, b2, w3t, b3, W4, b4, out);
}

// Round 9
// 408.310 us; speedup vs baseline: 1.0243x; 1.0243x over previous
//
#include <hip/hip_runtime.h>
#include <hip/hip_bf16.h>
#include <cstdint>
#include <cstddef>

typedef unsigned short u16;
typedef unsigned int u32;
typedef short short8 __attribute__((ext_vector_type(8)));
typedef short short4v __attribute__((ext_vector_type(4)));
typedef __bf16 bf16x8 __attribute__((ext_vector_type(8)));
typedef float v4f __attribute__((ext_vector_type(4)));
typedef float v16f __attribute__((ext_vector_type(16)));

#define NSAMP 65536
#define FEAT_PAD 1824   // 228 groups of 8

// ---- Layouts ----
// feats_t [rt=s>>4][g=kp>>3][r=s&15][e=kp&7]: elem addr = rt*29184 + g*128 + r*8 + e
// w1t_t   [ct=n>>4][g][c][e]:                 addr = ct*29184 + g*128 + c*8 + e
// h1      ROW-MAJOR [s][n] (65536 x 256)
// w2t_t   [ct][g][c][e] (128 cols, K=256):    addr = ct*4096  + g*128 + c*8 + e
// w3t_t   [ct][g][c][e] (64 cols, K=128):     addr = ct*2048  + g*128 + c*8 + e
// Intra-gram kp permutation (validated R3-R9):
//   kp in [512,1536): kp = 512 + lane*16 + rr  <-> orig 512 + i*32 + j,
//        j=lane&31, i=(rr&3)+8*(rr>>2)+4*(lane>>5)
//   kp in [1536,1792): kp = 1536 + lane*4 + rr <-> orig 1536 + i*16 + j,
//        j=lane&15, i=(lane>>4)*4+rr
//   sv at kp [1792,1808) natural, zeros [1808,1824)
// STORE DISCIPLINE (R2/R3): the 4 stores completing a lane's 64 B sector
// must issue back-to-back; any time-separation -> partial-line eviction ->
// WRITE amplification.
// STRUCTURE HISTORY: R5 fused feat = 147us local optimum (splits/ILP all
// regressed). R8 gemm1 dbuf via __syncthreads = NULL (vmcnt(0) drain per
// tile -- the documented m99/m100 ceiling). R9 gemm1: counted vmcnt(6) +
// raw s_barrier (T4, m218 lever): prefetch queue NEVER drains mid-loop;
// each STAGE gets two compute phases of latency cover.

__device__ __forceinline__ u16 f2bf(float f) {          // bit-twiddle RTNE (cold paths)
  union { float f; u32 u; } v; v.f = f;
  u32 r = (v.u + 0x7FFFu + ((v.u >> 16) & 1u)) >> 16;
  return (u16)r;
}
__device__ __forceinline__ u16 f2bf_h(float f) {        // HW RTNE cvt (hot paths)
  return __builtin_bit_cast(u16, (__bf16)f);
}
__device__ __forceinline__ float bf2f(u16 h) {
  union { u32 u; float f; } v; v.u = ((u32)h) << 16;
  return v.f;
}

__device__ __forceinline__ v4f mfma16(short8 a, short8 b, v4f c) {
  return __builtin_amdgcn_mfma_f32_16x16x32_bf16(
      __builtin_bit_cast(bf16x8, a), __builtin_bit_cast(bf16x8, b), c, 0, 0, 0);
}
__device__ __forceinline__ v16f mfma32(short8 a, short8 b, v16f c) {
  return __builtin_amdgcn_mfma_f32_32x32x16_bf16(
      __builtin_bit_cast(bf16x8, a), __builtin_bit_cast(bf16x8, b), c, 0, 0, 0);
}

// async global->LDS, 16 B/lane; per-lane global addr, wave-uniform LDS base
typedef __attribute__((address_space(1))) const void* gas_ptr;
typedef __attribute__((address_space(3))) void* las_ptr;
__device__ __forceinline__ void gl_lds16(const void* g, void* l) {
  __builtin_amdgcn_global_load_lds((gas_ptr)g, (las_ptr)l, 16, 0, 0);
}

// ---------------------------------------------------------------------------
// Weight prep -> fragment-tiled W1t/W2t/W3t. (unchanged)
// ---------------------------------------------------------------------------
__global__ void prep_kernel(const float* __restrict__ W1, const float* __restrict__ W2,
                            const float* __restrict__ W3,
                            u16* __restrict__ w1t, u16* __restrict__ w2t, u16* __restrict__ w3t) {
  int idx = blockIdx.x * 256 + threadIdx.x;
  if (idx < 256 * FEAT_PAD) {
    int n = idx / FEAT_PAD, kp = idx % FEAT_PAD;
    int k;
    if (kp < 512) {
      k = kp;
    } else if (kp < 1536) {
      int t = kp - 512, ln = t >> 4, rr = t & 15;
      int jj = ln & 31, q2 = ln >> 5;
      int i = (rr & 3) + 8 * (rr >> 2) + 4 * q2;
      k = 512 + i * 32 + jj;
    } else if (kp < 1792) {
      int t = kp - 1536, ln = t >> 2, rr = t & 3;
      int jj = ln & 15;
      int i = (ln >> 4) * 4 + rr;
      k = 1536 + i * 16 + jj;
    } else {
      k = kp;
    }
    size_t addr = (size_t)(n >> 4) * 29184 + (kp >> 3) * 128 + (n & 15) * 8 + (kp & 7);
    w1t[addr] = (kp < 1808) ? f2bf(W1[(size_t)k * 256 + n]) : (u16)0;
  }
  if (idx < 128 * 256) {
    int n = idx / 256, k = idx % 256;
    size_t addr = (size_t)(n >> 4) * 4096 + (k >> 3) * 128 + (n & 15) * 8 + (k & 7);
    w2t[addr] = f2bf(W2[k * 128 + n]);
  }
  if (idx < 64 * 128) {
    int n = idx / 128, k = idx % 128;
    size_t addr = (size_t)(n >> 4) * 2048 + (k >> 3) * 128 + (n & 15) * 8 + (k & 7);
    w3t[addr] = f2bf(W3[k * 64 + n]);
  }
}

// ---------------------------------------------------------------------------
// Fused SVD for 4 samples. R5 structure (LDS-pipe-lean):
// - Rotation transpose: 16 bpermutes; works on quad-rotation similarity
//   permutation of the gram (eigenvalues invariant; role jr=(j-4q)&15).
// - Broadcast-first Householder: 2 dependent shuffle stages/step; h, alpha,
//   beta, v computed locally in all lanes.
// - Division-free Sturm bisection (13 iters), dual-chain dots.
// ---------------------------------------------------------------------------
__device__ __forceinline__ void svd4(const v4f* aR, u16* tb, int s0, int lane) {
  const int j = lane & 15, bse = lane & 48, q = lane >> 4;
  const int jr = (j - 4 * q) & 15;          // role in the permuted frame
  int sig[16];                               // physical lane of role m
#pragma unroll
  for (int m = 0; m < 16; ++m) sig[m] = bse + ((m + 4 * q) & 15);

  // rotation transpose: a[c*4+r] = A'[c*4+r][jr] = A_q[((q+c)&3)*4+r][j]
  float a[16];
#pragma unroll
  for (int c = 0; c < 4; ++c) {
    const int srcq = (q - c) & 3;                 // sample reg this lane serves
    const int rd = ((q + c) & 3) * 16 + j;        // physical source lane
#pragma unroll
    for (int r = 0; r < 4; ++r) {
      float lo = (srcq & 1) ? aR[1][r] : aR[0][r];
      float hi = (srcq & 1) ? aR[3][r] : aR[2][r];
      float sel = (srcq & 2) ? hi : lo;
      a[c * 4 + r] = __shfl(sel, rd);
    }
  }

  float es[16];
#pragma unroll
  for (int i = 0; i < 16; ++i) es[i] = 0.f;

#pragma unroll
  for (int step = 0; step < 14; ++step) {
    const int i = 15 - step, l = i - 1;
    float xm = (jr <= l) ? a[i] : 0.f;
    // stage 1: broadcast row i (roles 0..l) to all lanes
    float xa[16];
#pragma unroll
    for (int m = 0; m < 16; ++m) xa[m] = (m < i) ? __shfl(xm, sig[m]) : 0.f;
    // h, alpha, beta computed redundantly (locally) in every lane
    float ha = 0.f, hb = 0.f;
#pragma unroll
    for (int m = 0; m < 16; m += 2) if (m < i) ha = fmaf(xa[m], xa[m], ha);
#pragma unroll
    for (int m = 1; m < 16; m += 2) if (m < i) hb = fmaf(xa[m], xa[m], hb);
    float h = ha + hb;
    float ul = xa[l];
    float sq = __builtin_amdgcn_sqrtf(h);
    float alpha = (ul >= 0.f) ? -sq : sq;
    float denom = h - ul * alpha;
    float beta = (h > 1e-30f) ? __builtin_amdgcn_rcpf(denom) : 0.f;
    float vq = (jr < l) ? xm : ((jr == l) ? (xm - alpha) : 0.f);
    xa[l] -= alpha;                      // xa[] now IS the v vector (m < i)
    es[i] = alpha;
    // p_j = beta * (A v)_j  (local dot, dual chain)
    float pa = 0.f, pb = 0.f;
#pragma unroll
    for (int m = 0; m < 16; m += 2) if (m < i) pa = fmaf(a[m], xa[m], pa);
#pragma unroll
    for (int m = 1; m < 16; m += 2) if (m < i) pb = fmaf(a[m], xa[m], pb);
    float p = (pa + pb) * beta;
    // stage 2: broadcast p (roles 0..l)
    float pp[16];
#pragma unroll
    for (int m = 0; m < 16; ++m) pp[m] = (m < i) ? __shfl(p, sig[m]) : 0.f;
    float Ka = 0.f, Kb = 0.f;
#pragma unroll
    for (int m = 0; m < 16; m += 2) if (m < i) Ka = fmaf(pp[m], xa[m], Ka);
#pragma unroll
    for (int m = 1; m < 16; m += 2) if (m < i) Kb = fmaf(pp[m], xa[m], Kb);
    float Ks = (Ka + Kb) * (0.5f * beta);
    float wsc = p - Ks * vq;             // this lane's w component
#pragma unroll
    for (int m = 0; m < 16; ++m) {
      if (m < i) {                       // row i skipped: entries dead after this step
        float wm = pp[m] - Ks * xa[m];
        a[m] -= xa[m] * wsc + wm * vq;
      }
    }
  }
  es[1] = __shfl(a[1], sig[0]);

  // diagonal broadcast (role m's diagonal from physical lane sig[m])
  float dd[16];
#pragma unroll
  for (int m = 0; m < 16; ++m) dd[m] = __shfl(a[m], sig[m]);
  float e2a[16];
  e2a[0] = 0.f;
#pragma unroll
  for (int k = 1; k < 16; ++k) e2a[k] = es[k] * es[k] + 1e-30f;
  float dmax = dd[0], emax = 0.f;
#pragma unroll
  for (int m = 1; m < 16; ++m) dmax = fmaxf(dmax, dd[m]);
#pragma unroll
  for (int k = 1; k < 16; ++k) emax = fmaxf(emax, fabsf(es[k]));

  // scale by 1/32 so det-recurrence magnitudes stay in fp32 range
  const float scl = 0.03125f;
#pragma unroll
  for (int m = 0; m < 16; ++m) dd[m] *= scl;
#pragma unroll
  for (int k = 1; k < 16; ++k) e2a[k] *= (scl * scl);

  float lo = 0.f, hi = (dmax + 2.f * emax + 1e-6f) * scl;
#pragma unroll 1
  for (int iter = 0; iter < 13; ++iter) {
    float mid = 0.5f * (lo + hi);
    // division-free Sturm: p_k = (d_k - mid) p_{k-1} - e2_k p_{k-2};
    // #eigs < mid = sign changes in (1, p_1, ..., p_16). Chain = 1 fma/step.
    float pm1 = 1.f, pc = dd[0] - mid;
    u32 cnt = __builtin_bit_cast(u32, pc) >> 31;
#pragma unroll
    for (int k = 1; k < 16; ++k) {
      float t = e2a[k] * pm1;
      float pn = fmaf(dd[k] - mid, pc, -t);
      cnt += ((__builtin_bit_cast(u32, pn) ^ __builtin_bit_cast(u32, pc)) >> 31);
      pm1 = pc; pc = pn;
    }
    if ((int)cnt > jr) hi = mid; else lo = mid;
  }
  float lam = 0.5f * (lo + hi) * 32.f;
  int t = 15 - jr;                      // descending order
  int s = s0 + q;                       // this quad's sample
  tb[(size_t)(224 + (t >> 3)) * 128 + (s & 15) * 8 + (t & 7)] =
      f2bf_h(__builtin_amdgcn_sqrtf(fmaxf(lam, 0.f)));
}

// ---------------------------------------------------------------------------
// Feature kernel: ONE 4-sample qtr per wave (16384 independent waves) WITH
// fused svd4 tail (R5-proven structure, 147 us). HW bf16 cvt in hot path.
// ---------------------------------------------------------------------------
__global__ __launch_bounds__(256) void feat_kernel(const float* __restrict__ x,
                                                   u16* __restrict__ feats) {
  const int lane = threadIdx.x & 63;
  const int wv = threadIdx.x >> 6;      // qtr index 0..3
  const int wid = blockIdx.x;           // tile 0..4095
  const int l15 = lane & 15, l31 = lane & 31, q4 = lane >> 4, q2 = lane >> 5;
  const int pbase = l15 * 32 + q4 * 8;
  u16* tb = feats + (size_t)wid * 29184;

  short8 sx[4], sc0[4], sc1[4];
  short4v sr4[4];
  v4f aR[4];
#pragma unroll
  for (int r8 = 0; r8 < 4; ++r8) {
    const int s = wid * 16 + wv * 4 + r8;
    const float* xs = x + (size_t)s * 512;
    float4 p0 = *(const float4*)(xs + pbase);
    float4 p1 = *(const float4*)(xs + pbase + 4);
    float t[8];
#pragma unroll
    for (int j = 0; j < 8; ++j) t[j] = xs[(q2 * 8 + j) * 32 + l31];

    short8 fp, ft;
    fp[0] = (short)f2bf_h(p0.x); fp[1] = (short)f2bf_h(p0.y);
    fp[2] = (short)f2bf_h(p0.z); fp[3] = (short)f2bf_h(p0.w);
    fp[4] = (short)f2bf_h(p1.x); fp[5] = (short)f2bf_h(p1.y);
    fp[6] = (short)f2bf_h(p1.z); fp[7] = (short)f2bf_h(p1.w);
#pragma unroll
    for (int j = 0; j < 8; ++j) ft[j] = (short)f2bf_h(t[j]);

    v4f accR; v16f accC;
#pragma unroll
    for (int r = 0; r < 4; ++r) accR[r] = 0.f;
#pragma unroll
    for (int r = 0; r < 16; ++r) accC[r] = 0.f;
    accR = mfma16(fp, fp, accR);   // Gr = P P^T (fp32)
    accC = mfma32(ft, ft, accC);   // Gc = P^T P

    sx[r8] = fp;
#pragma unroll
    for (int r = 0; r < 8; ++r) { sc0[r8][r] = (short)f2bf_h(accC[r]); sc1[r8][r] = (short)f2bf_h(accC[r + 8]); }
#pragma unroll
    for (int r = 0; r < 4; ++r) sr4[r8][r] = (short)f2bf_h(accR[r]);
    aR[r8] = accR;
  }

  // stores: all 4 hr per stream back-to-back; 4 waves co-write each 256 B
  // line concurrently (full-sector pattern, R1-proven)
  const int ho = wv * 4;
#pragma unroll
  for (int r8 = 0; r8 < 4; ++r8)
    *(short8*)(tb + (l15 * 4 + q4) * 128 + (ho + r8) * 8) = sx[r8];
#pragma unroll
  for (int r8 = 0; r8 < 4; ++r8)
    *(short8*)(tb + (64 + lane * 2) * 128 + (ho + r8) * 8) = sc0[r8];
#pragma unroll
  for (int r8 = 0; r8 < 4; ++r8)
    *(short8*)(tb + (65 + lane * 2) * 128 + (ho + r8) * 8) = sc1[r8];
#pragma unroll
  for (int r8 = 0; r8 < 4; ++r8)
    *(short4v*)(tb + (192 + (lane >> 1)) * 128 + (lane & 1) * 4 + (ho + r8) * 8) = sr4[r8];

  if (wv == 3 && lane < 32) {  // zero pad groups 226,227
    short8 z;
#pragma unroll
    for (int j = 0; j < 8; ++j) z[j] = 0;
    *(short8*)(tb + 226 * 128 + lane * 8) = z;
  }

  svd4(aR, tb, wid * 16 + ho, lane);  // sv for this wave's 4 samples
}

// ---------------------------------------------------------------------------
// GEMM1: h1 = relu(feats @ W1 + b1). M=65536, K=1824, N=256.
// R9: counted-vmcnt pipeline (T4). 2 LDS bufs (48 KB, 2 blocks/CU).
// Per tile: vmcnt(6) [STAGE(t) landed, STAGE(t+1) stays in flight] ->
// raw s_barrier -> ds_read+MFMA buf[t&1] -> raw s_barrier -> STAGE(t+2)
// into buf[t&1]. Queue never drains mid-loop; each STAGE has TWO compute
// phases of HBM-latency cover. Last tile peeled with vmcnt(0).
// ---------------------------------------------------------------------------
__global__ __launch_bounds__(256, 2) void gemm1_kernel(const u16* __restrict__ feats,
                                                       const u16* __restrict__ w1t,
                                                       const float* __restrict__ b1,
                                                       u16* __restrict__ h1) {
  __shared__ __align__(16) u16 At[2 * 8 * 512];    // 16 KB  [buf][rt_local][g][r][e]
  __shared__ __align__(16) u16 Bt[2 * 16 * 512];   // 32 KB  [buf][ct_local][g][c][e]
  const int tid = threadIdx.x, lane = tid & 63, wv = tid >> 6;
  const int l15 = lane & 15, q4 = lane >> 4;
  const int m0 = blockIdx.x * 128;
  const int wm = (wv & 1) * 64, wn = (wv >> 1) * 128;

  const u16* gA[2];
#pragma unroll
  for (int j = 0; j < 2; ++j)
    gA[j] = feats + (size_t)((m0 >> 4) + wv * 2 + j) * 29184 + lane * 8;
  const u16* gB[4];
#pragma unroll
  for (int j = 0; j < 4; ++j)
    gB[j] = w1t + (size_t)(wv * 4 + j) * 29184 + lane * 8;

  v4f acc[4][8];
#pragma unroll
  for (int mt = 0; mt < 4; ++mt)
#pragma unroll
    for (int nt = 0; nt < 8; ++nt)
#pragma unroll
      for (int r = 0; r < 4; ++r) acc[mt][nt][r] = 0.f;

  const int NT = FEAT_PAD / 32;          // 57 K-tiles

  // 6 loads/wave per stage
#define STAGE1(t, buf)                                                          \
  {                                                                             \
    const int _go = (t) * 512;                                                  \
    _Pragma("unroll")                                                           \
    for (int j = 0; j < 2; ++j)                                                 \
      gl_lds16(gA[j] + _go, At + (buf) * 4096 + (wv * 2 + j) * 512);            \
    _Pragma("unroll")                                                           \
    for (int j = 0; j < 4; ++j)                                                 \
      gl_lds16(gB[j] + _go, Bt + (buf) * 8192 + (wv * 4 + j) * 512);            \
  }

#define COMPUTE1(buf)                                                           \
  {                                                                             \
    const u16* Ab = At + (buf) * 4096;                                          \
    const u16* Bb = Bt + (buf) * 8192;                                          \
    short8 af[4], bfr[8];                                                       \
    _Pragma("unroll")                                                           \
    for (int mt = 0; mt < 4; ++mt)                                              \
      af[mt] = *(const short8*)(Ab + ((wv & 1) * 4 + mt) * 512 + q4 * 128 + l15 * 8); \
    _Pragma("unroll")                                                           \
    for (int nt = 0; nt < 8; ++nt)                                              \
      bfr[nt] = *(const short8*)(Bb + ((wv >> 1) * 8 + nt) * 512 + q4 * 128 + l15 * 8); \
    _Pragma("unroll")                                                           \
    for (int mt = 0; mt < 4; ++mt)                                              \
      _Pragma("unroll")                                                         \
      for (int nt = 0; nt < 8; ++nt)                                            \
        acc[mt][nt] = mfma16(af[mt], bfr[nt], acc[mt][nt]);                     \
  }

  // prologue: stage tiles 0,1 (12 outstanding loads/wave)
  STAGE1(0, 0);
  STAGE1(1, 1);

  int cur = 0;
#pragma unroll 1
  for (int t = 0; t < NT - 1; ++t) {
    asm volatile("s_waitcnt vmcnt(6)" ::: "memory");   // STAGE(t) landed
    __builtin_amdgcn_sched_barrier(0);
    __builtin_amdgcn_s_barrier();                      // all waves' STAGE(t) visible
    COMPUTE1(cur);
    __builtin_amdgcn_s_barrier();                      // all reads of buf[cur] done
    if (t + 2 < NT) STAGE1(t + 2, cur);                // overwrite safely
    cur ^= 1;
  }
  // peeled last tile: only STAGE(NT-1) in flight -> full drain
  asm volatile("s_waitcnt vmcnt(0)" ::: "memory");
  __builtin_amdgcn_sched_barrier(0);
  __builtin_amdgcn_s_barrier();
  COMPUTE1(cur);
#undef STAGE1
#undef COMPUTE1

  // epilogue: bias+relu, row-major h1 (proven full-sector pattern)
#pragma unroll
  for (int mt = 0; mt < 4; ++mt)
#pragma unroll
    for (int nt = 0; nt < 8; ++nt) {
      int col = wn + nt * 16 + l15;
      float bias = b1[col];
#pragma unroll
      for (int r = 0; r < 4; ++r) {
        int row = m0 + wm + mt * 16 + q4 * 4 + r;
        h1[(size_t)row * 256 + col] = f2bf_h(fmaxf(acc[mt][nt][r] + bias, 0.f));
      }
    }
}

// ---------------------------------------------------------------------------
// GEMM23: fused layers 2-4, barrier-free; A-frags from ROW-MAJOR h1. (unchanged)
// ---------------------------------------------------------------------------
__global__ __launch_bounds__(256, 2) void gemm23_kernel(
    const u16* __restrict__ h1, const u16* __restrict__ w2t, const float* __restrict__ b2,
    const u16* __restrict__ w3t, const float* __restrict__ b3,
    const float* __restrict__ w4, const float* __restrict__ b4, float* __restrict__ out) {
  __shared__ __align__(16) u16 H2[128 * 136];
  const int tid = threadIdx.x, lane = tid & 63, wv = tid >> 6;
  const int l15 = lane & 15, q4 = lane >> 4;
  const int m0 = blockIdx.x * 128;

  const u16* pA[2];
#pragma unroll
  for (int mt = 0; mt < 2; ++mt)
    pA[mt] = h1 + (size_t)(m0 + wv * 32 + mt * 16 + l15) * 256 + q4 * 8;
  const u16* pB[8];
#pragma unroll
  for (int nt = 0; nt < 8; ++nt)
    pB[nt] = w2t + (size_t)nt * 4096 + q4 * 128 + l15 * 8;

  v4f acc[2][8];
#pragma unroll
  for (int mt = 0; mt < 2; ++mt)
#pragma unroll
    for (int nt = 0; nt < 8; ++nt)
#pragma unroll
      for (int r = 0; r < 4; ++r) acc[mt][nt][r] = 0.f;

#pragma unroll
  for (int kk = 0; kk < 8; ++kk) {
    short8 af[2], bfr[8];
#pragma unroll
    for (int mt = 0; mt < 2; ++mt) af[mt] = *(const short8*)(pA[mt] + kk * 32);
#pragma unroll
    for (int nt = 0; nt < 8; ++nt) bfr[nt] = *(const short8*)(pB[nt] + kk * 512);
#pragma unroll
    for (int mt = 0; mt < 2; ++mt)
#pragma unroll
      for (int nt = 0; nt < 8; ++nt)
        acc[mt][nt] = mfma16(af[mt], bfr[nt], acc[mt][nt]);
  }

#pragma unroll
  for (int mt = 0; mt < 2; ++mt)
#pragma unroll
    for (int nt = 0; nt < 8; ++nt) {
      int c = nt * 16 + l15;
      float bias = b2[c];
#pragma unroll
      for (int r = 0; r < 4; ++r) {
        int rl = wv * 32 + mt * 16 + q4 * 4 + r;
        H2[rl * 136 + c] = f2bf_h(fmaxf(acc[mt][nt][r] + bias, 0.f));
      }
    }

  v4f acc2[2][4];
#pragma unroll
  for (int mt = 0; mt < 2; ++mt)
#pragma unroll
    for (int nt = 0; nt < 4; ++nt)
#pragma unroll
      for (int r = 0; r < 4; ++r) acc2[mt][nt][r] = 0.f;
#pragma unroll
  for (int kk = 0; kk < 4; ++kk) {
    short8 af2[2], bf2v[4];
#pragma unroll
    for (int mt = 0; mt < 2; ++mt)
      af2[mt] = *(const short8*)(H2 + (wv * 32 + mt * 16 + l15) * 136 + kk * 32 + q4 * 8);
#pragma unroll
    for (int nt = 0; nt < 4; ++nt)
      bf2v[nt] = *(const short8*)(w3t + (size_t)nt * 2048 + (kk * 4 + q4) * 128 + l15 * 8);
#pragma unroll
    for (int mt = 0; mt < 2; ++mt)
#pragma unroll
      for (int nt = 0; nt < 4; ++nt)
        acc2[mt][nt] = mfma16(af2[mt], bf2v[nt], acc2[mt][nt]);
  }

  float b4v = b4[0];
#pragma unroll
  for (int mt = 0; mt < 2; ++mt)
#pragma unroll
    for (int r = 0; r < 4; ++r) {
      float p = 0.f;
#pragma unroll
      for (int nt = 0; nt < 4; ++nt) {
        int c = nt * 16 + l15;
        float h3 = fmaxf(acc2[mt][nt][r] + b3[c], 0.f);
        p += h3 * w4[c];
      }
      p += __shfl_xor(p, 1);
      p += __shfl_xor(p, 2);
      p += __shfl_xor(p, 4);
      p += __shfl_xor(p, 8);
      if (l15 == 0) {
        int row = m0 + wv * 32 + mt * 16 + q4 * 4 + r;
        out[row] = p + b4v;
      }
    }
}

// ---------------------------------------------------------------------------
extern "C" void kernel_launch(void* const* d_in, const int* in_sizes, int n_in,
                              void* d_out, int out_size, void* d_ws, size_t ws_size,
                              hipStream_t stream) {
  const float* x  = (const float*)d_in[0];
  const float* W1 = (const float*)d_in[1];
  const float* b1 = (const float*)d_in[2];
  const float* W2 = (const float*)d_in[3];
  const float* b2 = (const float*)d_in[4];
  const float* W3 = (const float*)d_in[5];
  const float* b3 = (const float*)d_in[6];
  const float* W4 = (const float*)d_in[7];
  const float* b4 = (const float*)d_in[8];
  float* out = (float*)d_out;

  char* ws = (char*)d_ws;
  u16* feats = (u16*)ws;                                  // 239,075,328 B
  u16* h1    = (u16*)(ws + 239075328ull);                 //  33,554,432 B (row-major)
  u16* w1t   = (u16*)(ws + 239075328ull + 33554432ull);   //     933,888 B
  u16* w2t   = (u16*)(ws + 239075328ull + 33554432ull + 933888ull);            // 65,536
  u16* w3t   = (u16*)(ws + 239075328ull + 33554432ull + 933888ull + 65536ull); // 16,384

  prep_kernel<<<1824, 256, 0, stream>>>(W1, W2, W3, w1t, w2t, w3t);
  feat_kernel<<<4096, 256, 0, stream>>>(x, feats);
  gemm1_kernel<<<512, 256, 0, stream>>>(feats, w1t, b1, h1);
  gemm23_kernel<<<512, 256, 0, stream>>>(h1, w2t, b2, w3t, b3, W4, b4, out);
}

// Round 10
// 389.446 us; speedup vs baseline: 1.0739x; 1.0484x over previous
//
#include <hip/hip_runtime.h>
#include <hip/hip_bf16.h>
#include <cstdint>
#include <cstddef>

typedef unsigned short u16;
typedef unsigned int u32;
typedef short short8 __attribute__((ext_vector_type(8)));
typedef short short4v __attribute__((ext_vector_type(4)));
typedef __bf16 bf16x8 __attribute__((ext_vector_type(8)));
typedef float v4f __attribute__((ext_vector_type(4)));
typedef float v16f __attribute__((ext_vector_type(16)));

#define NSAMP 65536
#define FEAT_PAD 1824   // 228 groups of 8

// ---- Layouts ----
// feats_t [rt=s>>4][g=kp>>3][r=s&15][e=kp&7]: elem addr = rt*29184 + g*128 + r*8 + e
// w1t_t   [ct=n>>4][g][c][e]:                 addr = ct*29184 + g*128 + c*8 + e
// h1      ROW-MAJOR [s][n] (65536 x 256) -- L2-hot bounce buffer (fused MLP)
// w2t_t   [ct][g][c][e] (128 cols, K=256):    addr = ct*4096  + g*128 + c*8 + e
// w3t_t   [ct][g][c][e] (64 cols, K=128):     addr = ct*2048  + g*128 + c*8 + e
// STORE DISCIPLINE (R2/R3): the 4 stores completing a lane's 64 B sector
// must issue back-to-back; any time-separation -> partial-line eviction ->
// WRITE amplification.
// STRUCTURE HISTORY: R5 fused feat = local optimum (splits/ILP regressed).
// R8 dbuf-via-__syncthreads = NULL (vmcnt(0) drain per tile, m99/m100).
// R9 counted vmcnt(6) + raw s_barrier = real win (~95 -> ~61 us).
// R10: (a) gemm23 fused into gemm1 -- same block's h1 tile read back L2-hot;
// H2 LDS aliases the dead K-loop staging (48 KB total, 2 blocks/CU kept);
// (b) prep merged into feat's grid (blocks 4096+) -- hides ~10us + a launch.
// MEASUREMENT NOTE: cross-session feat dur has +/-15-25us machine-condition
// offset (preloaded flag correlates); judge rounds on totals.

__device__ __forceinline__ u16 f2bf(float f) {          // bit-twiddle RTNE (cold paths)
  union { float f; u32 u; } v; v.f = f;
  u32 r = (v.u + 0x7FFFu + ((v.u >> 16) & 1u)) >> 16;
  return (u16)r;
}
__device__ __forceinline__ u16 f2bf_h(float f) {        // HW RTNE cvt (hot paths)
  return __builtin_bit_cast(u16, (__bf16)f);
}
__device__ __forceinline__ float bf2f(u16 h) {
  union { u32 u; float f; } v; v.u = ((u32)h) << 16;
  return v.f;
}

__device__ __forceinline__ v4f mfma16(short8 a, short8 b, v4f c) {
  return __builtin_amdgcn_mfma_f32_16x16x32_bf16(
      __builtin_bit_cast(bf16x8, a), __builtin_bit_cast(bf16x8, b), c, 0, 0, 0);
}
__device__ __forceinline__ v16f mfma32(short8 a, short8 b, v16f c) {
  return __builtin_amdgcn_mfma_f32_32x32x16_bf16(
      __builtin_bit_cast(bf16x8, a), __builtin_bit_cast(bf16x8, b), c, 0, 0, 0);
}

// async global->LDS, 16 B/lane; per-lane global addr, wave-uniform LDS base
typedef __attribute__((address_space(1))) const void* gas_ptr;
typedef __attribute__((address_space(3))) void* las_ptr;
__device__ __forceinline__ void gl_lds16(const void* g, void* l) {
  __builtin_amdgcn_global_load_lds((gas_ptr)g, (las_ptr)l, 16, 0, 0);
}

// ---------------------------------------------------------------------------
// Fused SVD for 4 samples. R5 structure (LDS-pipe-lean):
// - Rotation transpose: 16 bpermutes; works on quad-rotation similarity
//   permutation of the gram (eigenvalues invariant; role jr=(j-4q)&15).
// - Broadcast-first Householder: 2 dependent shuffle stages/step; h, alpha,
//   beta, v computed locally in all lanes.
// - Division-free Sturm bisection (13 iters), dual-chain dots.
// ---------------------------------------------------------------------------
__device__ __forceinline__ void svd4(const v4f* aR, u16* tb, int s0, int lane) {
  const int j = lane & 15, bse = lane & 48, q = lane >> 4;
  const int jr = (j - 4 * q) & 15;          // role in the permuted frame
  int sig[16];                               // physical lane of role m
#pragma unroll
  for (int m = 0; m < 16; ++m) sig[m] = bse + ((m + 4 * q) & 15);

  // rotation transpose: a[c*4+r] = A'[c*4+r][jr] = A_q[((q+c)&3)*4+r][j]
  float a[16];
#pragma unroll
  for (int c = 0; c < 4; ++c) {
    const int srcq = (q - c) & 3;                 // sample reg this lane serves
    const int rd = ((q + c) & 3) * 16 + j;        // physical source lane
#pragma unroll
    for (int r = 0; r < 4; ++r) {
      float lo = (srcq & 1) ? aR[1][r] : aR[0][r];
      float hi = (srcq & 1) ? aR[3][r] : aR[2][r];
      float sel = (srcq & 2) ? hi : lo;
      a[c * 4 + r] = __shfl(sel, rd);
    }
  }

  float es[16];
#pragma unroll
  for (int i = 0; i < 16; ++i) es[i] = 0.f;

#pragma unroll
  for (int step = 0; step < 14; ++step) {
    const int i = 15 - step, l = i - 1;
    float xm = (jr <= l) ? a[i] : 0.f;
    // stage 1: broadcast row i (roles 0..l) to all lanes
    float xa[16];
#pragma unroll
    for (int m = 0; m < 16; ++m) xa[m] = (m < i) ? __shfl(xm, sig[m]) : 0.f;
    // h, alpha, beta computed redundantly (locally) in every lane
    float ha = 0.f, hb = 0.f;
#pragma unroll
    for (int m = 0; m < 16; m += 2) if (m < i) ha = fmaf(xa[m], xa[m], ha);
#pragma unroll
    for (int m = 1; m < 16; m += 2) if (m < i) hb = fmaf(xa[m], xa[m], hb);
    float h = ha + hb;
    float ul = xa[l];
    float sq = __builtin_amdgcn_sqrtf(h);
    float alpha = (ul >= 0.f) ? -sq : sq;
    float denom = h - ul * alpha;
    float beta = (h > 1e-30f) ? __builtin_amdgcn_rcpf(denom) : 0.f;
    float vq = (jr < l) ? xm : ((jr == l) ? (xm - alpha) : 0.f);
    xa[l] -= alpha;                      // xa[] now IS the v vector (m < i)
    es[i] = alpha;
    // p_j = beta * (A v)_j  (local dot, dual chain)
    float pa = 0.f, pb = 0.f;
#pragma unroll
    for (int m = 0; m < 16; m += 2) if (m < i) pa = fmaf(a[m], xa[m], pa);
#pragma unroll
    for (int m = 1; m < 16; m += 2) if (m < i) pb = fmaf(a[m], xa[m], pb);
    float p = (pa + pb) * beta;
    // stage 2: broadcast p (roles 0..l)
    float pp[16];
#pragma unroll
    for (int m = 0; m < 16; ++m) pp[m] = (m < i) ? __shfl(p, sig[m]) : 0.f;
    float Ka = 0.f, Kb = 0.f;
#pragma unroll
    for (int m = 0; m < 16; m += 2) if (m < i) Ka = fmaf(pp[m], xa[m], Ka);
#pragma unroll
    for (int m = 1; m < 16; m += 2) if (m < i) Kb = fmaf(pp[m], xa[m], Kb);
    float Ks = (Ka + Kb) * (0.5f * beta);
    float wsc = p - Ks * vq;             // this lane's w component
#pragma unroll
    for (int m = 0; m < 16; ++m) {
      if (m < i) {                       // row i skipped: entries dead after this step
        float wm = pp[m] - Ks * xa[m];
        a[m] -= xa[m] * wsc + wm * vq;
      }
    }
  }
  es[1] = __shfl(a[1], sig[0]);

  // diagonal broadcast (role m's diagonal from physical lane sig[m])
  float dd[16];
#pragma unroll
  for (int m = 0; m < 16; ++m) dd[m] = __shfl(a[m], sig[m]);
  float e2a[16];
  e2a[0] = 0.f;
#pragma unroll
  for (int k = 1; k < 16; ++k) e2a[k] = es[k] * es[k] + 1e-30f;
  float dmax = dd[0], emax = 0.f;
#pragma unroll
  for (int m = 1; m < 16; ++m) dmax = fmaxf(dmax, dd[m]);
#pragma unroll
  for (int k = 1; k < 16; ++k) emax = fmaxf(emax, fabsf(es[k]));

  // scale by 1/32 so det-recurrence magnitudes stay in fp32 range
  const float scl = 0.03125f;
#pragma unroll
  for (int m = 0; m < 16; ++m) dd[m] *= scl;
#pragma unroll
  for (int k = 1; k < 16; ++k) e2a[k] *= (scl * scl);

  float lo = 0.f, hi = (dmax + 2.f * emax + 1e-6f) * scl;
#pragma unroll 1
  for (int iter = 0; iter < 13; ++iter) {
    float mid = 0.5f * (lo + hi);
    // division-free Sturm: p_k = (d_k - mid) p_{k-1} - e2_k p_{k-2};
    // #eigs < mid = sign changes in (1, p_1, ..., p_16). Chain = 1 fma/step.
    float pm1 = 1.f, pc = dd[0] - mid;
    u32 cnt = __builtin_bit_cast(u32, pc) >> 31;
#pragma unroll
    for (int k = 1; k < 16; ++k) {
      float t = e2a[k] * pm1;
      float pn = fmaf(dd[k] - mid, pc, -t);
      cnt += ((__builtin_bit_cast(u32, pn) ^ __builtin_bit_cast(u32, pc)) >> 31);
      pm1 = pc; pc = pn;
    }
    if ((int)cnt > jr) hi = mid; else lo = mid;
  }
  float lam = 0.5f * (lo + hi) * 32.f;
  int t = 15 - jr;                      // descending order
  int s = s0 + q;                       // this quad's sample
  tb[(size_t)(224 + (t >> 3)) * 128 + (s & 15) * 8 + (t & 7)] =
      f2bf_h(__builtin_amdgcn_sqrtf(fmaxf(lam, 0.f)));
}

// ---------------------------------------------------------------------------
// Feature+prep kernel. Blocks 0..4095: R5-proven fused feature body (loads,
// MFMA grams, batched full-sector stores, svd4 tail). Blocks 4096..5919:
// weight-prep body (independent work; hides prep's ~10us + one launch under
// the feature phase). Stream order still guarantees w1t/w2t/w3t are ready
// before the MLP kernel.
// ---------------------------------------------------------------------------
__global__ __launch_bounds__(256) void featprep_kernel(
    const float* __restrict__ x, u16* __restrict__ feats,
    const float* __restrict__ W1, const float* __restrict__ W2,
    const float* __restrict__ W3,
    u16* __restrict__ w1t, u16* __restrict__ w2t, u16* __restrict__ w3t) {
  if (blockIdx.x >= 4096) {
    // ---- prep body ----
    int idx = (blockIdx.x - 4096) * 256 + threadIdx.x;
    if (idx < 256 * FEAT_PAD) {
      int n = idx / FEAT_PAD, kp = idx % FEAT_PAD;
      int k;
      if (kp < 512) {
        k = kp;
      } else if (kp < 1536) {
        int t = kp - 512, ln = t >> 4, rr = t & 15;
        int jj = ln & 31, q2 = ln >> 5;
        int i = (rr & 3) + 8 * (rr >> 2) + 4 * q2;
        k = 512 + i * 32 + jj;
      } else if (kp < 1792) {
        int t = kp - 1536, ln = t >> 2, rr = t & 3;
        int jj = ln & 15;
        int i = (ln >> 4) * 4 + rr;
        k = 1536 + i * 16 + jj;
      } else {
        k = kp;
      }
      size_t addr = (size_t)(n >> 4) * 29184 + (kp >> 3) * 128 + (n & 15) * 8 + (kp & 7);
      w1t[addr] = (kp < 1808) ? f2bf(W1[(size_t)k * 256 + n]) : (u16)0;
    }
    if (idx < 128 * 256) {
      int n = idx / 256, k = idx % 256;
      size_t addr = (size_t)(n >> 4) * 4096 + (k >> 3) * 128 + (n & 15) * 8 + (k & 7);
      w2t[addr] = f2bf(W2[k * 128 + n]);
    }
    if (idx < 64 * 128) {
      int n = idx / 128, k = idx % 128;
      size_t addr = (size_t)(n >> 4) * 2048 + (k >> 3) * 128 + (n & 15) * 8 + (k & 7);
      w3t[addr] = f2bf(W3[k * 64 + n]);
    }
    return;
  }

  // ---- feature body (R5-proven) ----
  const int lane = threadIdx.x & 63;
  const int wv = threadIdx.x >> 6;      // qtr index 0..3
  const int wid = blockIdx.x;           // tile 0..4095
  const int l15 = lane & 15, l31 = lane & 31, q4 = lane >> 4, q2 = lane >> 5;
  const int pbase = l15 * 32 + q4 * 8;
  u16* tb = feats + (size_t)wid * 29184;

  short8 sx[4], sc0[4], sc1[4];
  short4v sr4[4];
  v4f aR[4];
#pragma unroll
  for (int r8 = 0; r8 < 4; ++r8) {
    const int s = wid * 16 + wv * 4 + r8;
    const float* xs = x + (size_t)s * 512;
    float4 p0 = *(const float4*)(xs + pbase);
    float4 p1 = *(const float4*)(xs + pbase + 4);
    float t[8];
#pragma unroll
    for (int j = 0; j < 8; ++j) t[j] = xs[(q2 * 8 + j) * 32 + l31];

    short8 fp, ft;
    fp[0] = (short)f2bf_h(p0.x); fp[1] = (short)f2bf_h(p0.y);
    fp[2] = (short)f2bf_h(p0.z); fp[3] = (short)f2bf_h(p0.w);
    fp[4] = (short)f2bf_h(p1.x); fp[5] = (short)f2bf_h(p1.y);
    fp[6] = (short)f2bf_h(p1.z); fp[7] = (short)f2bf_h(p1.w);
#pragma unroll
    for (int j = 0; j < 8; ++j) ft[j] = (short)f2bf_h(t[j]);

    v4f accR; v16f accC;
#pragma unroll
    for (int r = 0; r < 4; ++r) accR[r] = 0.f;
#pragma unroll
    for (int r = 0; r < 16; ++r) accC[r] = 0.f;
    accR = mfma16(fp, fp, accR);   // Gr = P P^T (fp32)
    accC = mfma32(ft, ft, accC);   // Gc = P^T P

    sx[r8] = fp;
#pragma unroll
    for (int r = 0; r < 8; ++r) { sc0[r8][r] = (short)f2bf_h(accC[r]); sc1[r8][r] = (short)f2bf_h(accC[r + 8]); }
#pragma unroll
    for (int r = 0; r < 4; ++r) sr4[r8][r] = (short)f2bf_h(accR[r]);
    aR[r8] = accR;
  }

  // stores: all 4 hr per stream back-to-back; 4 waves co-write each 256 B
  // line concurrently (full-sector pattern, R1-proven)
  const int ho = wv * 4;
#pragma unroll
  for (int r8 = 0; r8 < 4; ++r8)
    *(short8*)(tb + (l15 * 4 + q4) * 128 + (ho + r8) * 8) = sx[r8];
#pragma unroll
  for (int r8 = 0; r8 < 4; ++r8)
    *(short8*)(tb + (64 + lane * 2) * 128 + (ho + r8) * 8) = sc0[r8];
#pragma unroll
  for (int r8 = 0; r8 < 4; ++r8)
    *(short8*)(tb + (65 + lane * 2) * 128 + (ho + r8) * 8) = sc1[r8];
#pragma unroll
  for (int r8 = 0; r8 < 4; ++r8)
    *(short4v*)(tb + (192 + (lane >> 1)) * 128 + (lane & 1) * 4 + (ho + r8) * 8) = sr4[r8];

  if (wv == 3 && lane < 32) {  // zero pad groups 226,227
    short8 z;
#pragma unroll
    for (int j = 0; j < 8; ++j) z[j] = 0;
    *(short8*)(tb + 226 * 128 + lane * 8) = z;
  }

  svd4(aR, tb, wid * 16 + ho, lane);  // sv for this wave's 4 samples
}

// ---------------------------------------------------------------------------
// Fused MLP: layers 1-4 in one kernel. Per block: 128-sample tile.
// Phase 1 (R9-exact counted-vmcnt K-loop): h1_tile = relu(feats@W1+b1) in
// acc; epilogue stores to h1 (HBM addr, L2-resident). __syncthreads() drains
// stores; Phase 2 (gemm23 body) reads the SAME tile back L2-hot, H2 LDS
// ALIASES the dead staging buffer (48 KB total -> 2 blocks/CU preserved).
// ---------------------------------------------------------------------------
__global__ __launch_bounds__(256, 2) void mlp_kernel(
    const u16* __restrict__ feats, const u16* __restrict__ w1t,
    const float* __restrict__ b1, u16* __restrict__ h1,
    const u16* __restrict__ w2t, const float* __restrict__ b2,
    const u16* __restrict__ w3t, const float* __restrict__ b3,
    const float* __restrict__ w4, const float* __restrict__ b4,
    float* __restrict__ out) {
  __shared__ __align__(16) u16 SMEM[24576];   // 48 KB: staging, then H2 alias
  u16* At = SMEM;            // 2*8*512  u16 (16 KB)
  u16* Bt = SMEM + 8192;     // 2*16*512 u16 (32 KB)
  const int tid = threadIdx.x, lane = tid & 63, wv = tid >> 6;
  const int l15 = lane & 15, q4 = lane >> 4;
  const int m0 = blockIdx.x * 128;
  const int wm = (wv & 1) * 64, wn = (wv >> 1) * 128;

  const u16* gA[2];
#pragma unroll
  for (int j = 0; j < 2; ++j)
    gA[j] = feats + (size_t)((m0 >> 4) + wv * 2 + j) * 29184 + lane * 8;
  const u16* gB[4];
#pragma unroll
  for (int j = 0; j < 4; ++j)
    gB[j] = w1t + (size_t)(wv * 4 + j) * 29184 + lane * 8;

  v4f acc[4][8];
#pragma unroll
  for (int mt = 0; mt < 4; ++mt)
#pragma unroll
    for (int nt = 0; nt < 8; ++nt)
#pragma unroll
      for (int r = 0; r < 4; ++r) acc[mt][nt][r] = 0.f;

  const int NT = FEAT_PAD / 32;          // 57 K-tiles

#define STAGE1(t, buf)                                                          \
  {                                                                             \
    const int _go = (t) * 512;                                                  \
    _Pragma("unroll")                                                           \
    for (int j = 0; j < 2; ++j)                                                 \
      gl_lds16(gA[j] + _go, At + (buf) * 4096 + (wv * 2 + j) * 512);            \
    _Pragma("unroll")                                                           \
    for (int j = 0; j < 4; ++j)                                                 \
      gl_lds16(gB[j] + _go, Bt + (buf) * 8192 + (wv * 4 + j) * 512);            \
  }

#define COMPUTE1(buf)                                                           \
  {                                                                             \
    const u16* Ab = At + (buf) * 4096;                                          \
    const u16* Bb = Bt + (buf) * 8192;                                          \
    short8 af[4], bfr[8];                                                       \
    _Pragma("unroll")                                                           \
    for (int mt = 0; mt < 4; ++mt)                                              \
      af[mt] = *(const short8*)(Ab + ((wv & 1) * 4 + mt) * 512 + q4 * 128 + l15 * 8); \
    _Pragma("unroll")                                                           \
    for (int nt = 0; nt < 8; ++nt)                                              \
      bfr[nt] = *(const short8*)(Bb + ((wv >> 1) * 8 + nt) * 512 + q4 * 128 + l15 * 8); \
    _Pragma("unroll")                                                           \
    for (int mt = 0; mt < 4; ++mt)                                              \
      _Pragma("unroll")                                                         \
      for (int nt = 0; nt < 8; ++nt)                                            \
        acc[mt][nt] = mfma16(af[mt], bfr[nt], acc[mt][nt]);                     \
  }

  // prologue: stage tiles 0,1 (12 outstanding loads/wave)
  STAGE1(0, 0);
  STAGE1(1, 1);

  int cur = 0;
#pragma unroll 1
  for (int t = 0; t < NT - 1; ++t) {
    asm volatile("s_waitcnt vmcnt(6)" ::: "memory");   // STAGE(t) landed
    __builtin_amdgcn_sched_barrier(0);
    __builtin_amdgcn_s_barrier();                      // all waves' STAGE(t) visible
    COMPUTE1(cur);
    __builtin_amdgcn_s_barrier();                      // all reads of buf[cur] done
    if (t + 2 < NT) STAGE1(t + 2, cur);                // overwrite safely
    cur ^= 1;
  }
  asm volatile("s_waitcnt vmcnt(0)" ::: "memory");
  __builtin_amdgcn_sched_barrier(0);
  __builtin_amdgcn_s_barrier();
  COMPUTE1(cur);
#undef STAGE1
#undef COMPUTE1

  // layer-1 epilogue: bias+relu -> h1 tile (row-major; stays in this XCD's L2)
#pragma unroll
  for (int mt = 0; mt < 4; ++mt)
#pragma unroll
    for (int nt = 0; nt < 8; ++nt) {
      int col = wn + nt * 16 + l15;
      float bias = b1[col];
#pragma unroll
      for (int r = 0; r < 4; ++r) {
        int row = m0 + wm + mt * 16 + q4 * 4 + r;
        h1[(size_t)row * 256 + col] = f2bf_h(fmaxf(acc[mt][nt][r] + bias, 0.f));
      }
    }

  __syncthreads();   // drain h1 stores (vmcnt 0) + barrier: tile visible to all waves

  // ---- phase 2: layers 2-4 on this block's OWN h1 tile (L2-hot) ----
  u16* H2 = SMEM;    // aliases dead staging (needs 34,816 B <= 49,152 B)

  const u16* pA[2];
#pragma unroll
  for (int mt = 0; mt < 2; ++mt)
    pA[mt] = h1 + (size_t)(m0 + wv * 32 + mt * 16 + l15) * 256 + q4 * 8;
  const u16* pB[8];
#pragma unroll
  for (int nt = 0; nt < 8; ++nt)
    pB[nt] = w2t + (size_t)nt * 4096 + q4 * 128 + l15 * 8;

  v4f acc1[2][8];
#pragma unroll
  for (int mt = 0; mt < 2; ++mt)
#pragma unroll
    for (int nt = 0; nt < 8; ++nt)
#pragma unroll
      for (int r = 0; r < 4; ++r) acc1[mt][nt][r] = 0.f;

#pragma unroll
  for (int kk = 0; kk < 8; ++kk) {
    short8 af[2], bfr[8];
#pragma unroll
    for (int mt = 0; mt < 2; ++mt) af[mt] = *(const short8*)(pA[mt] + kk * 32);
#pragma unroll
    for (int nt = 0; nt < 8; ++nt) bfr[nt] = *(const short8*)(pB[nt] + kk * 512);
#pragma unroll
    for (int mt = 0; mt < 2; ++mt)
#pragma unroll
      for (int nt = 0; nt < 8; ++nt)
        acc1[mt][nt] = mfma16(af[mt], bfr[nt], acc1[mt][nt]);
  }

#pragma unroll
  for (int mt = 0; mt < 2; ++mt)
#pragma unroll
    for (int nt = 0; nt < 8; ++nt) {
      int c = nt * 16 + l15;
      float bias = b2[c];
#pragma unroll
      for (int r = 0; r < 4; ++r) {
        int rl = wv * 32 + mt * 16 + q4 * 4 + r;
        H2[rl * 136 + c] = f2bf_h(fmaxf(acc1[mt][nt][r] + bias, 0.f));
      }
    }
  __syncthreads();   // H2 complete before layer-3 reads

  v4f acc2[2][4];
#pragma unroll
  for (int mt = 0; mt < 2; ++mt)
#pragma unroll
    for (int nt = 0; nt < 4; ++nt)
#pragma unroll
      for (int r = 0; r < 4; ++r) acc2[mt][nt][r] = 0.f;
#pragma unroll
  for (int kk = 0; kk < 4; ++kk) {
    short8 af2[2], bf2v[4];
#pragma unroll
    for (int mt = 0; mt < 2; ++mt)
      af2[mt] = *(const short8*)(H2 + (wv * 32 + mt * 16 + l15) * 136 + kk * 32 + q4 * 8);
#pragma unroll
    for (int nt = 0; nt < 4; ++nt)
      bf2v[nt] = *(const short8*)(w3t + (size_t)nt * 2048 + (kk * 4 + q4) * 128 + l15 * 8);
#pragma unroll
    for (int mt = 0; mt < 2; ++mt)
#pragma unroll
      for (int nt = 0; nt < 4; ++nt)
        acc2[mt][nt] = mfma16(af2[mt], bf2v[nt], acc2[mt][nt]);
  }

  float b4v = b4[0];
#pragma unroll
  for (int mt = 0; mt < 2; ++mt)
#pragma unroll
    for (int r = 0; r < 4; ++r) {
      float p = 0.f;
#pragma unroll
      for (int nt = 0; nt < 4; ++nt) {
        int c = nt * 16 + l15;
        float h3 = fmaxf(acc2[mt][nt][r] + b3[c], 0.f);
        p += h3 * w4[c];
      }
      p += __shfl_xor(p, 1);
      p += __shfl_xor(p, 2);
      p += __shfl_xor(p, 4);
      p += __shfl_xor(p, 8);
      if (l15 == 0) {
        int row = m0 + wv * 32 + mt * 16 + q4 * 4 + r;
        out[row] = p + b4v;
      }
    }
}

// ---------------------------------------------------------------------------
extern "C" void kernel_launch(void* const* d_in, const int* in_sizes, int n_in,
                              void* d_out, int out_size, void* d_ws, size_t ws_size,
                              hipStream_t stream) {
  const float* x  = (const float*)d_in[0];
  const float* W1 = (const float*)d_in[1];
  const float* b1 = (const float*)d_in[2];
  const float* W2 = (const float*)d_in[3];
  const float* b2 = (const float*)d_in[4];
  const float* W3 = (const float*)d_in[5];
  const float* b3 = (const float*)d_in[6];
  const float* W4 = (const float*)d_in[7];
  const float* b4 = (const float*)d_in[8];
  float* out = (float*)d_out;

  char* ws = (char*)d_ws;
  u16* feats = (u16*)ws;                                  // 239,075,328 B
  u16* h1    = (u16*)(ws + 239075328ull);                 //  33,554,432 B (L2 bounce)
  u16* w1t   = (u16*)(ws + 239075328ull + 33554432ull);   //     933,888 B
  u16* w2t   = (u16*)(ws + 239075328ull + 33554432ull + 933888ull);            // 65,536
  u16* w3t   = (u16*)(ws + 239075328ull + 33554432ull + 933888ull + 65536ull); // 16,384

  featprep_kernel<<<4096 + 1824, 256, 0, stream>>>(x, feats, W1, W2, W3, w1t, w2t, w3t);
  mlp_kernel<<<512, 256, 0, stream>>>(feats, w1t, b1, h1, w2t, b2, w3t, b3, W4, b4, out);
}